// Round 8
// baseline (438.610 us; speedup 1.0000x reference)
//
#include <hip/hip_runtime.h>

#define DD 256
#define TT 4096
#define BB 32

typedef __attribute__((ext_vector_type(8))) short short8;   // 8 bf16 (4 VGPR)
typedef __attribute__((ext_vector_type(4))) float floatx4;  // MFMA acc

// ---------- bf16 helpers (RNE via bit twiddle) ----------
__device__ __forceinline__ unsigned short f2bf(float f) {
    unsigned u = __builtin_bit_cast(unsigned, f);
    unsigned r = u + 0x7FFFu + ((u >> 16) & 1u);
    return (unsigned short)(r >> 16);
}
__device__ __forceinline__ float bf2f(unsigned short h) {
    return __builtin_bit_cast(float, (unsigned)h << 16);
}
__device__ __forceinline__ float2 unpk(unsigned u) {
    float2 r;
    r.x = __builtin_bit_cast(float, u << 16);
    r.y = __builtin_bit_cast(float, u & 0xFFFF0000u);
    return r;
}

#define GLDS16(g, l)                                                        \
    __builtin_amdgcn_global_load_lds(                                       \
        (const __attribute__((address_space(1))) void*)(g),                 \
        (__attribute__((address_space(3))) void*)(l), 16, 0, 0)

// ======================= merged prep: X->bf16 panels, W split+T, acc=0 =====
// Xp layout: [k/32][row][k%32]  (panel stride 131072*32 elements)
// Wt layout per plane: [half][k/32][n][k%32]  (half stride 65536)
__global__ __launch_bounds__(256)
void prep_kernel(const float* __restrict__ X,
                 const float* __restrict__ Wq, const float* __restrict__ Wk,
                 const float* __restrict__ Wv,
                 unsigned short* __restrict__ Xp, unsigned short* __restrict__ Wt,
                 float* __restrict__ acc)
{
    const int bid = blockIdx.x;
    const int tid = threadIdx.x;
    if (bid < 16384) {
        size_t i = ((size_t)bid * 256 + tid) * 8;
        float4 a = *(const float4*)(X + i);
        float4 b = *(const float4*)(X + i + 4);
        short8 o;
        o[0] = (short)f2bf(a.x); o[1] = (short)f2bf(a.y);
        o[2] = (short)f2bf(a.z); o[3] = (short)f2bf(a.w);
        o[4] = (short)f2bf(b.x); o[5] = (short)f2bf(b.y);
        o[6] = (short)f2bf(b.z); o[7] = (short)f2bf(b.w);
        size_t row = i >> 8;
        int k = (int)(i & 255);
        size_t off = (size_t)(k >> 5) * (131072u * 32u) + row * 32 + (k & 31);
        *(short8*)(Xp + off) = o;
    } else if (bid < 16384 + 768) {
        const int wb = bid - 16384;
        const int z = wb >> 8;
        const int k = wb & 255;
        const int n = tid;
        const float* W = (z == 0) ? Wq : (z == 1) ? Wk : Wv;
        float w = W[k * 256 + n];
        unsigned short hi = f2bf(w);
        unsigned short lo = f2bf(w - bf2f(hi));
        size_t base = (size_t)z * 131072;
        size_t off = (size_t)(k >> 5) * 8192 + (size_t)n * 32 + (k & 31);
        Wt[base +         off] = hi;
        Wt[base + 65536 + off] = lo;
    } else {
        for (int i = tid; i < BB * DD; i += 256) acc[i] = 0.f;
    }
}

// ======================= QKV GEMM: C = xh@Wh + xh@Wl (bf16 MFMA) ===========
// Double-buffered LDS (one barrier per K-step, staging overlaps MFMA) +
// chunk-XOR swizzle (c ^= (row>>1)&3 on 16B chunks) on BOTH sides.
// 1D grid (6144) with bijective XCD-aware remap: all 6 (z,col) blocks that
// share a 128-row A-panel get the same d%8 -> same XCD -> panel fetched into
// that XCD's L2 once (presumed round-robin dispatch; a wrong mapping only
// affects speed, not correctness).
__global__ __launch_bounds__(256, 3)
void qkv_mfma_kernel(const unsigned short* __restrict__ Xp,
                     const unsigned short* __restrict__ Wt,
                     const float* __restrict__ bq, const float* __restrict__ bk,
                     const float* __restrict__ bv,
                     unsigned short* __restrict__ Q, unsigned short* __restrict__ Kp,
                     unsigned short* __restrict__ V)
{
    // decode: d -> (xcd x, m, zc); r = x + 8m; zc = z*2 + c
    const int d = blockIdx.x;
    const int x = d & 7, t = d >> 3;
    const int m = t / 6, zc = t - 6 * m;
    const int z = zc >> 1;
    const int col0 = (zc & 1) * 128;
    const size_t row0 = (size_t)(x + 8 * m) * 128;

    const unsigned short* Wz = Wt + (size_t)z * 131072;
    const float* bias = (z == 0) ? bq : (z == 1) ? bk : bv;
    unsigned short* Y = (z == 0) ? Q : (z == 1) ? Kp : V;

    // [0,16K): A dbuf (2 x 8KB)   [16K,48K): B dbuf (2 x 16KB)
    __shared__ __align__(16) unsigned char smem[49152];

    const int tid = threadIdx.x;
    const int lane = tid & 63, wave = tid >> 6;
    const int wm = wave & 1, wn = wave >> 1;
    const int l15 = lane & 15, lq = lane >> 4;

    floatx4 acc[4][4];
    #pragma unroll
    for (int i = 0; i < 4; ++i)
        #pragma unroll
        for (int j = 0; j < 4; ++j)
            acc[i][j] = (floatx4){0.f, 0.f, 0.f, 0.f};

    // stage K-panel p (k0 = p*32) into buffer parity pb
    auto stage = [&](int p, int pb) {
        unsigned short* As = (unsigned short*)(smem + pb * 8192);
        unsigned short* Bs = (unsigned short*)(smem + 16384 + pb * 16384);
        const unsigned short* Ap = Xp + (size_t)p * (131072u * 32u);
        const unsigned short* Bp = Wz + (size_t)p * 8192;
        #pragma unroll
        for (int it = 0; it < 2; ++it) {
            int flat = it * 256 + tid;
            int mm = flat >> 2, c = flat & 3;
            int sc = c ^ ((mm >> 1) & 3);
            GLDS16(Ap + (row0 + mm) * 32 + sc * 8, As + flat * 8);
        }
        #pragma unroll
        for (int half = 0; half < 2; ++half)
            #pragma unroll
            for (int it = 0; it < 2; ++it) {
                int flat = it * 256 + tid;
                int n = flat >> 2, c = flat & 3;
                int sc = c ^ ((n >> 1) & 3);
                GLDS16(Bp + half * 65536 + (size_t)(col0 + n) * 32 + sc * 8,
                       Bs + half * 4096 + flat * 8);
            }
    };

    stage(0, 0);
    __syncthreads();

    for (int k = 0; k < 8; ++k) {
        const int pb = k & 1;
        if (k < 7) stage(k + 1, pb ^ 1);

        const unsigned short* As = (const unsigned short*)(smem + pb * 8192);
        const unsigned short* Bs = (const unsigned short*)(smem + 16384 + pb * 16384);

        short8 a[4];
        #pragma unroll
        for (int mt = 0; mt < 4; ++mt) {
            int row = wm * 64 + mt * 16 + l15;
            a[mt] = *(const short8*)(As + row * 32 + (lq ^ ((row >> 1) & 3)) * 8);
        }
        #pragma unroll
        for (int nt = 0; nt < 4; ++nt) {
            int nr = wn * 64 + nt * 16 + l15;
            const unsigned short* bp = Bs + nr * 32 + (lq ^ ((nr >> 1) & 3)) * 8;
            short8 bh = *(const short8*)bp;
            short8 bl = *(const short8*)(bp + 4096);
            #pragma unroll
            for (int mt = 0; mt < 4; ++mt) {
                acc[mt][nt] = __builtin_amdgcn_mfma_f32_16x16x32_bf16(a[mt], bh, acc[mt][nt], 0, 0, 0);
                acc[mt][nt] = __builtin_amdgcn_mfma_f32_16x16x32_bf16(a[mt], bl, acc[mt][nt], 0, 0, 0);
            }
        }
        __syncthreads();   // drains this iter's stage (hidden under the MFMAs)
    }

    // epilogue: per-wave LDS transpose then vectorized global store
    unsigned short* Cs = (unsigned short*)(smem + wave * 8192); // [64][64] bf16
    #pragma unroll
    for (int nt = 0; nt < 4; ++nt) {
        float bv_ = bias[col0 + wn * 64 + nt * 16 + l15];
        #pragma unroll
        for (int mt = 0; mt < 4; ++mt)
            #pragma unroll
            for (int r = 0; r < 4; ++r) {
                int row = mt * 16 + lq * 4 + r;
                Cs[row * 64 + nt * 16 + l15] = f2bf(acc[mt][nt][r] + bv_);
            }
    }
    #pragma unroll
    for (int p = 0; p < 8; ++p) {
        int row = p * 8 + (lane >> 3);
        float4 dd = *(const float4*)(Cs + row * 64 + (lane & 7) * 8);
        *(float4*)(Y + (row0 + wm * 64 + row) * 256 + col0 + wn * 64 + (lane & 7) * 8) = dd;
    }
}

// ======================= fused 3-scale attention ===========================
// gelu2(x) = 2*gelu(x); 0.5 folded into cwh. A-S 7.1.26 erf (|err|<=1.5e-7).
__device__ __forceinline__ float gelu2(float x) {
    float z = fabsf(x) * 0.70710678118654752f;
    float t = __builtin_amdgcn_rcpf(fmaf(z, 0.3275911f, 1.0f));
    float p = fmaf(t, 1.061405429f, -1.453152027f);
    p = fmaf(p, t, 1.421413741f);
    p = fmaf(p, t, -0.284496736f);
    p = fmaf(p, t, 0.254829592f);
    p = p * t;
    float e = __expf(-z * z);
    float erf_abs = fmaf(-p, e, 1.0f);
    float erfv = copysignf(erf_abs, x);
    return x * (1.0f + erfv);
}
__device__ __forceinline__ void addu4(uint4 d, float* f) {
    float2 t;
    t = unpk(d.x); f[0] += t.x; f[1] += t.y;
    t = unpk(d.y); f[2] += t.x; f[3] += t.y;
    t = unpk(d.z); f[4] += t.x; f[5] += t.y;
    t = unpk(d.w); f[6] += t.x; f[7] += t.y;
}

#define SPAN 32
#define NROW 34            // span + 2 leading ghost rows

// ---- generic-path pooled gathers (rows packed as bytes in rp) ----
template<int KS>
__device__ __forceinline__ void pool_qk(const unsigned short* __restrict__ qb,
                                        const unsigned short* __restrict__ kb,
                                        int rp,
                                        float* __restrict__ qf,
                                        float* __restrict__ kf)
{
    #pragma unroll
    for (int j = 0; j < KS; ++j) {
        int ra = (rp >> (8 * j)) & 0xFF;
        uint4 qd = *(const uint4*)(qb + ra * 256);
        uint4 kd = *(const uint4*)(kb + ra * 256);
        addu4(qd, qf);
        addu4(kd, kf);
    }
}

template<int KS>
__device__ __forceinline__ void pool_v(const unsigned short* __restrict__ vb,
                                       int rp, float* __restrict__ vf)
{
    #pragma unroll
    for (int j = 0; j < KS; ++j) {
        int ra = (rp >> (8 * j)) & 0xFF;
        uint4 vd = *(const uint4*)(vb + ra * 256);
        addu4(vd, vf);
    }
}

// ---- fast-path unit: rows = rowbase + i*KS + j (compile-time i,j offsets),
// no bounds, no reflect. Valid for s in [1,126] (no boundary positions).
template<int KS>
__device__ __forceinline__ void fast_unit(const unsigned short* __restrict__ qkvs,
                                          int rowbase,
                                          const float* __restrict__ cwh,
                                          float sscale, float inv_k, int fperm,
                                          float* __restrict__ accL)
{
    float S[4][4];
    #pragma unroll
    for (int i = 0; i < 4; ++i)
        #pragma unroll
        for (int j = 0; j < 4; ++j) S[i][j] = 0.f;

    #pragma unroll
    for (int half = 0; half < 2; ++half) {
        const unsigned short* qb = qkvs + half * 128 + fperm + rowbase * 256;
        const unsigned short* kb = qb + NROW * 256;
        float qf[4][8], kf[4][8];
        #pragma unroll
        for (int i = 0; i < 4; ++i) {
            #pragma unroll
            for (int e = 0; e < 8; ++e) { qf[i][e] = 0.f; kf[i][e] = 0.f; }
            #pragma unroll
            for (int j = 0; j < KS; ++j) {
                addu4(*(const uint4*)(qb + (i * KS + j) * 256), qf[i]);
                addu4(*(const uint4*)(kb + (i * KS + j) * 256), kf[i]);
            }
        }
        #pragma unroll
        for (int i = 0; i < 4; ++i)
            #pragma unroll
            for (int j = 0; j < 4; ++j) {
                float d = 0.f;
                #pragma unroll
                for (int e = 0; e < 8; ++e) d = fmaf(qf[i][e], kf[j][e], d);
                S[i][j] += d;
            }
    }
    #pragma unroll
    for (int i = 0; i < 4; ++i)
        #pragma unroll
        for (int j = 0; j < 4; ++j) {
            float t = S[i][j];
            t += __shfl_xor(t, 1, 64);
            t += __shfl_xor(t, 2, 64);
            S[i][j] = t * sscale;
        }
    float P[4][4];
    #pragma unroll
    for (int i = 0; i < 4; ++i) {
        float m = fmaxf(fmaxf(S[i][0], S[i][1]), fmaxf(S[i][2], S[i][3]));
        float e0 = __expf(S[i][0] - m), e1 = __expf(S[i][1] - m);
        float e2 = __expf(S[i][2] - m), e3 = __expf(S[i][3] - m);
        float inv = inv_k * __builtin_amdgcn_rcpf(e0 + e1 + e2 + e3);
        P[i][0] = e0 * inv; P[i][1] = e1 * inv; P[i][2] = e2 * inv; P[i][3] = e3 * inv;
    }
    #pragma unroll
    for (int half = 0; half < 2; ++half) {
        const unsigned short* vb =
            qkvs + 2 * NROW * 256 + half * 128 + fperm + rowbase * 256;
        float vf[4][8];
        #pragma unroll
        for (int i = 0; i < 4; ++i) {
            #pragma unroll
            for (int e = 0; e < 8; ++e) vf[i][e] = 0.f;
            #pragma unroll
            for (int j = 0; j < KS; ++j)
                addu4(*(const uint4*)(vb + (i * KS + j) * 256), vf[i]);
        }
        #pragma unroll
        for (int i = 0; i < 4; ++i) {
            #pragma unroll
            for (int e = 0; e < 8; ++e) {
                float o = P[i][0]*vf[0][e] + P[i][1]*vf[1][e]
                        + P[i][2]*vf[2][e] + P[i][3]*vf[3][e];
                accL[half * 8 + e] += cwh[i] * gelu2(o);
            }
        }
    }
}

// Block = (span s, batch b). 256 threads = 64 units x 4 lanes.
// Fast path (s in [1,126]): affine static rows, no bounds/reflect machinery.
// Generic path (s==0 or 127): full rp/vmask/reflect handling.
// End: LDS-scratch block reduction (2 barriers), ONE atomic per thread.
__global__ __launch_bounds__(256, 3)
void attn_fused_kernel(const unsigned short* __restrict__ Q,
                       const unsigned short* __restrict__ K,
                       const unsigned short* __restrict__ V,
                       float* __restrict__ acc)
{
    __shared__ __align__(16) unsigned char smem[3 * NROW * 256 * 2];  // 52224 B
    unsigned short* qkvs = (unsigned short*)smem;       // [3][NROW][256] permuted
    float* scratch = (float*)smem;                      // [16][256] overlay

    const int tid = threadIdx.x;
    const int s = blockIdx.x;          // span within batch (0..127)
    const int b = blockIdx.y;
    const int r0 = s * SPAN;
    const int rbase = r0 - 2;

    // ---- stage Q,K,V via global_load_lds; source chunk index pre-permuted --
    #pragma unroll
    for (int t = 0; t < 3; ++t) {
        const unsigned short* src =
            ((t == 0) ? Q : (t == 1) ? K : V) + (size_t)b * TT * DD;
        #pragma unroll
        for (int it = 0; it < 5; ++it) {
            int flat = it * 256 + tid;              // 0..1279, need 0..1087
            if (flat < NROW * 32) {
                int row = flat >> 5, dc = flat & 31;
                int g = rbase + row;
                g = (g < 0) ? 0 : g;                 // only span 0 clamps (unused rows)
                int c = (((dc >> 2) & 3) << 3) | ((dc & 3) << 1) | ((dc >> 4) & 1);
                GLDS16(src + (size_t)g * DD + c * 8,
                       qkvs + t * (NROW * 256) + flat * 8);
            }
        }
    }
    __syncthreads();

    // ---- unit decode (waves are scale-uniform except wave 3 edge units) ----
    const int slot = tid >> 2, lq = tid & 3;
    const int head = slot & 3, u = slot >> 2;     // u = 0..15
    int ksize, LEN, w; bool active = true;
    if (u < 8)       { ksize = 1; LEN = 4096; w = s * 8 + u; }
    else if (u < 12) { ksize = 2; LEN = 2049; w = s * 4 + (u - 8); }
    else if (u < 14) { ksize = 4; LEN = 1025; w = s * 2 + (u - 12); }
    else if (u == 14){ ksize = 2; LEN = 2049; w = 512; active = (s == 127); }
    else             { ksize = 4; LEN = 1025; w = 256; active = (s == 127); }

    const int f0 = head * 64 + lq * 16;           // global feat offset
    const int fperm = head * 32 + lq * 8;         // permuted LDS in-row offset

    float accL[16];
    #pragma unroll
    for (int e = 0; e < 16; ++e) accL[e] = 0.f;

    const bool generic = (s == 0) || (s == 127);

    if (!generic) {
        // -------- fast path: rows affine in u, all positions interior -------
        if (active) {                     // u14/u15 inactive here
            float cwh[4];
            if (ksize == 1) {
                #pragma unroll
                for (int i = 0; i < 4; ++i) cwh[i] = 0.5f;
                fast_unit<1>(qkvs, u * 4 + 2, cwh, 0.125f, 1.0f, fperm, accL);
            } else if (ksize == 2) {
                #pragma unroll
                for (int i = 0; i < 4; ++i) {
                    int p = 16 * s + 4 * (u - 8) + i;
                    cwh[i] = 0.5f * (float)(((p + 1) * TT + 2048) / 2049
                                          - (p * TT + 2048) / 2049);
                }
                fast_unit<2>(qkvs, 8 * (u - 8) + 1, cwh, 0.03125f, 0.5f, fperm, accL);
            } else {
                #pragma unroll
                for (int i = 0; i < 4; ++i) {
                    int p = 8 * s + 4 * (u - 12) + i;
                    cwh[i] = 0.5f * (float)(((p + 1) * TT + 1024) / 1025
                                          - (p * TT + 1024) / 1025);
                }
                fast_unit<4>(qkvs, 16 * (u - 12), cwh, 0.0078125f, 0.25f, fperm, accL);
            }
        }
    } else if (active) {
        // -------- generic path: boundary reflect + edge windows -------------
        int rp[4]; float cwh[4]; int vmask = 0;
        for (int i = 0; i < 4; ++i) {
            int p = w * 4 + i;
            bool vv = (p < LEN);
            if (vv) vmask |= (1 << i);
            int pc = vv ? p : 0;
            int r[4] = {0, 0, 0, 0};
            if (ksize == 1) { r[0] = pc; }
            else if (ksize == 2) {
                if (pc == 0)            { r[0] = 0;      r[1] = 1;      }
                else if (pc == LEN - 1) { r[0] = TT - 2; r[1] = TT - 1; }
                else                    { r[0] = 2 * pc - 1; r[1] = 2 * pc; }
            } else {
                if (pc == 0)            { r[0] = 2; r[1] = 1; r[2] = 0; r[3] = 1; }
                else if (pc == LEN - 1) { r[0] = TT - 3; r[1] = TT - 2; r[2] = TT - 2; r[3] = TT - 1; }
                else                    { r[0] = 4*pc - 2; r[1] = 4*pc - 1; r[2] = 4*pc; r[3] = 4*pc + 1; }
            }
            int rr = 0;
            #pragma unroll
            for (int j = 0; j < 4; ++j) rr |= ((r[j] - rbase) & 0xFF) << (8 * j);
            rp[i] = rr;
            float c = 0.5f;
            if (ksize == 2)
                c = 0.5f * (float)(((p + 1) * TT + 2048) / 2049 - (p * TT + 2048) / 2049);
            else if (ksize == 4)
                c = 0.5f * (float)(((p + 1) * TT + 1024) / 1025 - (p * TT + 1024) / 1025);
            cwh[i] = vv ? c : 0.f;
        }
        const float inv_k = 1.0f / (float)ksize;
        const float sscale = 0.125f * inv_k * inv_k;

        float S[4][4];
        #pragma unroll
        for (int i = 0; i < 4; ++i)
            #pragma unroll
            for (int j = 0; j < 4; ++j) S[i][j] = 0.f;

        for (int half = 0; half < 2; ++half) {
            float qf[4][8], kf[4][8];
            const unsigned short* qb = qkvs + half * 128 + fperm;
            const unsigned short* kb = qb + NROW * 256;
            #pragma unroll
            for (int i = 0; i < 4; ++i) {
                #pragma unroll
                for (int e = 0; e < 8; ++e) { qf[i][e] = 0.f; kf[i][e] = 0.f; }
                if (vmask & (1 << i)) {
                    if (ksize == 1)      pool_qk<1>(qb, kb, rp[i], qf[i], kf[i]);
                    else if (ksize == 2) pool_qk<2>(qb, kb, rp[i], qf[i], kf[i]);
                    else                 pool_qk<4>(qb, kb, rp[i], qf[i], kf[i]);
                }
            }
            #pragma unroll
            for (int i = 0; i < 4; ++i)
                #pragma unroll
                for (int j = 0; j < 4; ++j) {
                    float d = 0.f;
                    #pragma unroll
                    for (int e = 0; e < 8; ++e) d = fmaf(qf[i][e], kf[j][e], d);
                    S[i][j] += d;
                }
        }
        #pragma unroll
        for (int i = 0; i < 4; ++i)
            #pragma unroll
            for (int j = 0; j < 4; ++j) {
                float t = S[i][j];
                t += __shfl_xor(t, 1, 64);
                t += __shfl_xor(t, 2, 64);
                S[i][j] = t * sscale;
            }
        float P[4][4];
        #pragma unroll
        for (int i = 0; i < 4; ++i) {
            float m = fmaxf(fmaxf(S[i][0], S[i][1]), fmaxf(S[i][2], S[i][3]));
            float e0 = __expf(S[i][0] - m), e1 = __expf(S[i][1] - m);
            float e2 = __expf(S[i][2] - m), e3 = __expf(S[i][3] - m);
            float inv = inv_k * __builtin_amdgcn_rcpf(e0 + e1 + e2 + e3);
            P[i][0] = e0 * inv; P[i][1] = e1 * inv; P[i][2] = e2 * inv; P[i][3] = e3 * inv;
        }
        for (int half = 0; half < 2; ++half) {
            float vf[4][8];
            const unsigned short* vb = qkvs + 2 * NROW * 256 + half * 128 + fperm;
            #pragma unroll
            for (int i = 0; i < 4; ++i) {
                #pragma unroll
                for (int e = 0; e < 8; ++e) vf[i][e] = 0.f;
                if (vmask & (1 << i)) {
                    if (ksize == 1)      pool_v<1>(vb, rp[i], vf[i]);
                    else if (ksize == 2) pool_v<2>(vb, rp[i], vf[i]);
                    else                 pool_v<4>(vb, rp[i], vf[i]);
                }
            }
            #pragma unroll
            for (int i = 0; i < 4; ++i) {
                if (!(vmask & (1 << i))) continue;
                #pragma unroll
                for (int e = 0; e < 8; ++e) {
                    float o = P[i][0]*vf[0][e] + P[i][1]*vf[1][e]
                            + P[i][2]*vf[2][e] + P[i][3]*vf[3][e];
                    accL[half * 8 + e] += cwh[i] * gelu2(o);
                }
            }
        }
    }

    // ---- block reduction over the 16 window-units, one atomic per feat ----
    __syncthreads();   // all qkvs reads done; reuse LDS as scratch
    #pragma unroll
    for (int e = 0; e < 16; e += 4) {
        float4 d = {accL[e], accL[e+1], accL[e+2], accL[e+3]};
        *(float4*)(scratch + u * 256 + f0 + e) = d;
    }
    __syncthreads();
    float sum = 0.f;
    #pragma unroll
    for (int uu = 0; uu < 16; ++uu) sum += scratch[uu * 256 + tid];
    atomicAdd(&acc[b * DD + tid], sum);
}

// ======================= classifier head ===================================
__global__ __launch_bounds__(256)
void classifier_kernel(const float* __restrict__ acc,
                       const float* __restrict__ Wp,  const float* __restrict__ bp,
                       const float* __restrict__ Wc1, const float* __restrict__ bc1,
                       const float* __restrict__ Wc2, const float* __restrict__ bc2,
                       float* __restrict__ out)
{
    const int b = blockIdx.x;
    const int d = threadIdx.x;
    __shared__ float sm[256], sf[256], sh[256];

    sm[d] = acc[b * 256 + d] * (1.0f / 4096.0f);
    __syncthreads();

    float s = bp[d];
    for (int kk = 0; kk < 256; ++kk) s = fmaf(sm[kk], Wp[kk * 256 + d], s);
    sf[d] = s;
    __syncthreads();

    s = bc1[d];
    for (int kk = 0; kk < 256; ++kk) s = fmaf(sf[kk], Wc1[kk * 256 + d], s);
    sh[d] = fmaxf(s, 0.0f);
    __syncthreads();

    if (d < 7) {
        s = bc2[d];
        for (int kk = 0; kk < 256; ++kk) s = fmaf(sh[kk], Wc2[kk * 7 + d], s);
        out[b * 7 + d] = s;
    }
}

// ======================= launch ============================================
extern "C" void kernel_launch(void* const* d_in, const int* in_sizes, int n_in,
                              void* d_out, int out_size, void* d_ws, size_t ws_size,
                              hipStream_t stream)
{
    const float* x   = (const float*)d_in[0];
    const float* Wq  = (const float*)d_in[1];
    const float* bq  = (const float*)d_in[2];
    const float* Wk  = (const float*)d_in[3];
    const float* bk  = (const float*)d_in[4];
    const float* Wv  = (const float*)d_in[5];
    const float* bv  = (const float*)d_in[6];
    const float* Wp  = (const float*)d_in[7];
    const float* bp  = (const float*)d_in[8];
    const float* Wc1 = (const float*)d_in[9];
    const float* bc1 = (const float*)d_in[10];
    const float* Wc2 = (const float*)d_in[11];
    const float* bc2 = (const float*)d_in[12];
    float* out = (float*)d_out;

    const size_t plane = (size_t)BB * TT * DD;
    unsigned short* Q  = (unsigned short*)d_ws;
    unsigned short* K  = Q + plane;
    unsigned short* V  = K + plane;
    unsigned short* Xh = V + plane;
    unsigned short* Wt = Xh + plane;
    float* acc = (float*)(Wt + 3 * 131072);

    prep_kernel<<<dim3(16384 + 768 + 1), 256, 0, stream>>>(
        x, Wq, Wk, Wv, Xh, Wt, acc);

    qkv_mfma_kernel<<<dim3(6144), 256, 0, stream>>>(
        Xh, Wt, bq, bk, bv, Q, K, V);

    attn_fused_kernel<<<dim3(128, BB), 256, 0, stream>>>(Q, K, V, acc);

    classifier_kernel<<<dim3(BB), 256, 0, stream>>>(acc, Wp, bp, Wc1, bc1, Wc2, bc2, out);
}

// Round 9
// 436.629 us; speedup vs baseline: 1.0045x; 1.0045x over previous
//
#include <hip/hip_runtime.h>

#define DD 256
#define TT 4096
#define BB 32

typedef __attribute__((ext_vector_type(8))) short short8;   // 8 bf16 (4 VGPR)
typedef __attribute__((ext_vector_type(4))) float floatx4;  // MFMA acc

// ---------- bf16 helpers (RNE via bit twiddle) ----------
__device__ __forceinline__ unsigned short f2bf(float f) {
    unsigned u = __builtin_bit_cast(unsigned, f);
    unsigned r = u + 0x7FFFu + ((u >> 16) & 1u);
    return (unsigned short)(r >> 16);
}
__device__ __forceinline__ float bf2f(unsigned short h) {
    return __builtin_bit_cast(float, (unsigned)h << 16);
}
__device__ __forceinline__ float2 unpk(unsigned u) {
    float2 r;
    r.x = __builtin_bit_cast(float, u << 16);
    r.y = __builtin_bit_cast(float, u & 0xFFFF0000u);
    return r;
}

#define GLDS16(g, l)                                                        \
    __builtin_amdgcn_global_load_lds(                                       \
        (const __attribute__((address_space(1))) void*)(g),                 \
        (__attribute__((address_space(3))) void*)(l), 16, 0, 0)

// ======================= merged prep: X->bf16 panels, W split+T, acc=0 =====
// Xp layout: [k/32][row][k%32]  (panel stride 131072*32 elements)
// Wt layout per plane: [half][k/32][n][k%32]  (half stride 65536)
__global__ __launch_bounds__(256)
void prep_kernel(const float* __restrict__ X,
                 const float* __restrict__ Wq, const float* __restrict__ Wk,
                 const float* __restrict__ Wv,
                 unsigned short* __restrict__ Xp, unsigned short* __restrict__ Wt,
                 float* __restrict__ acc)
{
    const int bid = blockIdx.x;
    const int tid = threadIdx.x;
    if (bid < 16384) {
        size_t i = ((size_t)bid * 256 + tid) * 8;
        float4 a = *(const float4*)(X + i);
        float4 b = *(const float4*)(X + i + 4);
        short8 o;
        o[0] = (short)f2bf(a.x); o[1] = (short)f2bf(a.y);
        o[2] = (short)f2bf(a.z); o[3] = (short)f2bf(a.w);
        o[4] = (short)f2bf(b.x); o[5] = (short)f2bf(b.y);
        o[6] = (short)f2bf(b.z); o[7] = (short)f2bf(b.w);
        size_t row = i >> 8;
        int k = (int)(i & 255);
        size_t off = (size_t)(k >> 5) * (131072u * 32u) + row * 32 + (k & 31);
        *(short8*)(Xp + off) = o;
    } else if (bid < 16384 + 768) {
        const int wb = bid - 16384;
        const int z = wb >> 8;
        const int k = wb & 255;
        const int n = tid;
        const float* W = (z == 0) ? Wq : (z == 1) ? Wk : Wv;
        float w = W[k * 256 + n];
        unsigned short hi = f2bf(w);
        unsigned short lo = f2bf(w - bf2f(hi));
        size_t base = (size_t)z * 131072;
        size_t off = (size_t)(k >> 5) * 8192 + (size_t)n * 32 + (k & 31);
        Wt[base +         off] = hi;
        Wt[base + 65536 + off] = lo;
    } else {
        for (int i = tid; i < BB * DD; i += 256) acc[i] = 0.f;
    }
}

// ======================= QKV GEMM: C = xh@Wh + xh@Wl (bf16 MFMA) ===========
// 16 half-steps: hi/lo weight panels alternate as K-steps (Bhi->bbuf0,
// Blo->bbuf1), A panel double-buffered and shared by the pair. LDS 32 KB
// (was 49 KB) -> register/LDS budget allows 4 blocks/CU. Chunk-XOR swizzle
// (c ^= (row>>1)&3) on BOTH global source and ds_read. XCD-aware bijective
// block remap: 6 (z,col) blocks sharing an A-panel get the same d%8.
__global__ __launch_bounds__(256, 4)
void qkv_mfma_kernel(const unsigned short* __restrict__ Xp,
                     const unsigned short* __restrict__ Wt,
                     const float* __restrict__ bq, const float* __restrict__ bk,
                     const float* __restrict__ bv,
                     unsigned short* __restrict__ Q, unsigned short* __restrict__ Kp,
                     unsigned short* __restrict__ V)
{
    // decode: d -> (xcd x, m, zc); row-panel = x + 8m; zc = z*2 + c
    const int d = blockIdx.x;
    const int x = d & 7, t = d >> 3;
    const int m = t / 6, zc = t - 6 * m;
    const int z = zc >> 1;
    const int col0 = (zc & 1) * 128;
    const size_t row0 = (size_t)(x + 8 * m) * 128;

    const unsigned short* Wz = Wt + (size_t)z * 131072;
    const float* bias = (z == 0) ? bq : (z == 1) ? bk : bv;
    unsigned short* Y = (z == 0) ? Q : (z == 1) ? Kp : V;

    // [0,16K): A dbuf (2 x 8KB)   [16K,32K): B dbuf (2 x 8KB)
    __shared__ __align__(16) unsigned char smem[32768];

    const int tid = threadIdx.x;
    const int lane = tid & 63, wave = tid >> 6;
    const int wm = wave & 1, wn = wave >> 1;
    const int l15 = lane & 15, lq = lane >> 4;

    floatx4 acc[4][4];
    #pragma unroll
    for (int i = 0; i < 4; ++i)
        #pragma unroll
        for (int j = 0; j < 4; ++j)
            acc[i][j] = (floatx4){0.f, 0.f, 0.f, 0.f};

    auto stageA = [&](int p, int ap) {
        unsigned short* As = (unsigned short*)(smem + ap * 8192);
        const unsigned short* Apt = Xp + (size_t)p * (131072u * 32u);
        #pragma unroll
        for (int it = 0; it < 2; ++it) {
            int flat = it * 256 + tid;
            int mm = flat >> 2, c = flat & 3;
            int sc = c ^ ((mm >> 1) & 3);
            GLDS16(Apt + (row0 + mm) * 32 + sc * 8, As + flat * 8);
        }
    };
    auto stageB = [&](int p, int half, int bp) {
        unsigned short* Bs = (unsigned short*)(smem + 16384 + bp * 8192);
        const unsigned short* Bp = Wz + (size_t)half * 65536 + (size_t)p * 8192;
        #pragma unroll
        for (int it = 0; it < 2; ++it) {
            int flat = it * 256 + tid;
            int n = flat >> 2, c = flat & 3;
            int sc = c ^ ((n >> 1) & 3);
            GLDS16(Bp + (size_t)(col0 + n) * 32 + sc * 8, Bs + flat * 8);
        }
    };

    // per-half-step compute: 4 A + 4 B ds_read_b128, 16 MFMAs
    auto compute = [&](int ap, int bp) {
        const unsigned short* As = (const unsigned short*)(smem + ap * 8192);
        const unsigned short* Bs = (const unsigned short*)(smem + 16384 + bp * 8192);
        short8 a[4];
        #pragma unroll
        for (int mt = 0; mt < 4; ++mt) {
            int row = wm * 64 + mt * 16 + l15;
            a[mt] = *(const short8*)(As + row * 32 + (lq ^ ((row >> 1) & 3)) * 8);
        }
        #pragma unroll
        for (int nt = 0; nt < 4; ++nt) {
            int nr = wn * 64 + nt * 16 + l15;
            short8 bfrag = *(const short8*)(Bs + nr * 32 + (lq ^ ((nr >> 1) & 3)) * 8);
            #pragma unroll
            for (int mt = 0; mt < 4; ++mt)
                acc[mt][nt] = __builtin_amdgcn_mfma_f32_16x16x32_bf16(
                    a[mt], bfrag, acc[mt][nt], 0, 0, 0);
        }
    };

    stageA(0, 0);
    stageB(0, 0, 0);          // hi panels live in bbuf0, lo panels in bbuf1
    __syncthreads();

    for (int p = 0; p < 8; ++p) {
        const int ap = p & 1;
        // ---- hi half-step: prefetch lo(p) into bbuf1, compute with bbuf0 ---
        stageB(p, 1, 1);
        compute(ap, 0);
        __syncthreads();
        // ---- lo half-step: prefetch A(p+1)+hi(p+1), compute with bbuf1 -----
        if (p < 7) {
            stageA(p + 1, ap ^ 1);
            stageB(p + 1, 0, 0);
        }
        compute(ap, 1);
        __syncthreads();
    }

    // epilogue: per-wave LDS transpose then vectorized global store (32 KB reuse)
    unsigned short* Cs = (unsigned short*)(smem + wave * 8192); // [64][64] bf16
    #pragma unroll
    for (int nt = 0; nt < 4; ++nt) {
        float bv_ = bias[col0 + wn * 64 + nt * 16 + l15];
        #pragma unroll
        for (int mt = 0; mt < 4; ++mt)
            #pragma unroll
            for (int r = 0; r < 4; ++r) {
                int row = mt * 16 + lq * 4 + r;
                Cs[row * 64 + nt * 16 + l15] = f2bf(acc[mt][nt][r] + bv_);
            }
    }
    #pragma unroll
    for (int p = 0; p < 8; ++p) {
        int row = p * 8 + (lane >> 3);
        float4 dd = *(const float4*)(Cs + row * 64 + (lane & 7) * 8);
        *(float4*)(Y + (row0 + wm * 64 + row) * 256 + col0 + wn * 64 + (lane & 7) * 8) = dd;
    }
}

// ======================= fused 3-scale attention ===========================
// gelu2(x) = 2*gelu(x); 0.5 folded into cwh. A-S 7.1.26 erf (|err|<=1.5e-7).
__device__ __forceinline__ float gelu2(float x) {
    float z = fabsf(x) * 0.70710678118654752f;
    float t = __builtin_amdgcn_rcpf(fmaf(z, 0.3275911f, 1.0f));
    float p = fmaf(t, 1.061405429f, -1.453152027f);
    p = fmaf(p, t, 1.421413741f);
    p = fmaf(p, t, -0.284496736f);
    p = fmaf(p, t, 0.254829592f);
    p = p * t;
    float e = __expf(-z * z);
    float erf_abs = fmaf(-p, e, 1.0f);
    float erfv = copysignf(erf_abs, x);
    return x * (1.0f + erfv);
}
__device__ __forceinline__ void addu4(uint4 d, float* f) {
    float2 t;
    t = unpk(d.x); f[0] += t.x; f[1] += t.y;
    t = unpk(d.y); f[2] += t.x; f[3] += t.y;
    t = unpk(d.z); f[4] += t.x; f[5] += t.y;
    t = unpk(d.w); f[6] += t.x; f[7] += t.y;
}

#define SPAN 32
#define NROW 34            // span + 2 leading ghost rows

// ---- generic-path pooled gathers (rows packed as bytes in rp) ----
template<int KS>
__device__ __forceinline__ void pool_qk(const unsigned short* __restrict__ qb,
                                        const unsigned short* __restrict__ kb,
                                        int rp,
                                        float* __restrict__ qf,
                                        float* __restrict__ kf)
{
    #pragma unroll
    for (int j = 0; j < KS; ++j) {
        int ra = (rp >> (8 * j)) & 0xFF;
        uint4 qd = *(const uint4*)(qb + ra * 256);
        uint4 kd = *(const uint4*)(kb + ra * 256);
        addu4(qd, qf);
        addu4(kd, kf);
    }
}

template<int KS>
__device__ __forceinline__ void pool_v(const unsigned short* __restrict__ vb,
                                       int rp, float* __restrict__ vf)
{
    #pragma unroll
    for (int j = 0; j < KS; ++j) {
        int ra = (rp >> (8 * j)) & 0xFF;
        uint4 vd = *(const uint4*)(vb + ra * 256);
        addu4(vd, vf);
    }
}

// ---- fast-path unit: rows = rowbase + i*KS + j (compile-time i,j offsets),
// no bounds, no reflect. Valid for s in [1,126] (no boundary positions).
template<int KS>
__device__ __forceinline__ void fast_unit(const unsigned short* __restrict__ qkvs,
                                          int rowbase,
                                          const float* __restrict__ cwh,
                                          float sscale, float inv_k, int fperm,
                                          float* __restrict__ accL)
{
    float S[4][4];
    #pragma unroll
    for (int i = 0; i < 4; ++i)
        #pragma unroll
        for (int j = 0; j < 4; ++j) S[i][j] = 0.f;

    #pragma unroll
    for (int half = 0; half < 2; ++half) {
        const unsigned short* qb = qkvs + half * 128 + fperm + rowbase * 256;
        const unsigned short* kb = qb + NROW * 256;
        float qf[4][8], kf[4][8];
        #pragma unroll
        for (int i = 0; i < 4; ++i) {
            #pragma unroll
            for (int e = 0; e < 8; ++e) { qf[i][e] = 0.f; kf[i][e] = 0.f; }
            #pragma unroll
            for (int j = 0; j < KS; ++j) {
                addu4(*(const uint4*)(qb + (i * KS + j) * 256), qf[i]);
                addu4(*(const uint4*)(kb + (i * KS + j) * 256), kf[i]);
            }
        }
        #pragma unroll
        for (int i = 0; i < 4; ++i)
            #pragma unroll
            for (int j = 0; j < 4; ++j) {
                float d = 0.f;
                #pragma unroll
                for (int e = 0; e < 8; ++e) d = fmaf(qf[i][e], kf[j][e], d);
                S[i][j] += d;
            }
    }
    #pragma unroll
    for (int i = 0; i < 4; ++i)
        #pragma unroll
        for (int j = 0; j < 4; ++j) {
            float t = S[i][j];
            t += __shfl_xor(t, 1, 64);
            t += __shfl_xor(t, 2, 64);
            S[i][j] = t * sscale;
        }
    float P[4][4];
    #pragma unroll
    for (int i = 0; i < 4; ++i) {
        float m = fmaxf(fmaxf(S[i][0], S[i][1]), fmaxf(S[i][2], S[i][3]));
        float e0 = __expf(S[i][0] - m), e1 = __expf(S[i][1] - m);
        float e2 = __expf(S[i][2] - m), e3 = __expf(S[i][3] - m);
        float inv = inv_k * __builtin_amdgcn_rcpf(e0 + e1 + e2 + e3);
        P[i][0] = e0 * inv; P[i][1] = e1 * inv; P[i][2] = e2 * inv; P[i][3] = e3 * inv;
    }
    #pragma unroll
    for (int half = 0; half < 2; ++half) {
        const unsigned short* vb =
            qkvs + 2 * NROW * 256 + half * 128 + fperm + rowbase * 256;
        float vf[4][8];
        #pragma unroll
        for (int i = 0; i < 4; ++i) {
            #pragma unroll
            for (int e = 0; e < 8; ++e) vf[i][e] = 0.f;
            #pragma unroll
            for (int j = 0; j < KS; ++j)
                addu4(*(const uint4*)(vb + (i * KS + j) * 256), vf[i]);
        }
        #pragma unroll
        for (int i = 0; i < 4; ++i) {
            #pragma unroll
            for (int e = 0; e < 8; ++e) {
                float o = P[i][0]*vf[0][e] + P[i][1]*vf[1][e]
                        + P[i][2]*vf[2][e] + P[i][3]*vf[3][e];
                accL[half * 8 + e] += cwh[i] * gelu2(o);
            }
        }
    }
}

// Block = (span s, batch b). 256 threads = 64 units x 4 lanes.
// Fast path (s in [1,126]): affine static rows, no bounds/reflect machinery.
// Generic path (s==0 or 127): full rp/vmask/reflect handling.
// End: LDS-scratch block reduction (2 barriers), ONE atomic per thread.
__global__ __launch_bounds__(256, 3)
void attn_fused_kernel(const unsigned short* __restrict__ Q,
                       const unsigned short* __restrict__ K,
                       const unsigned short* __restrict__ V,
                       float* __restrict__ acc)
{
    __shared__ __align__(16) unsigned char smem[3 * NROW * 256 * 2];  // 52224 B
    unsigned short* qkvs = (unsigned short*)smem;       // [3][NROW][256] permuted
    float* scratch = (float*)smem;                      // [16][256] overlay

    const int tid = threadIdx.x;
    const int s = blockIdx.x;          // span within batch (0..127)
    const int b = blockIdx.y;
    const int r0 = s * SPAN;
    const int rbase = r0 - 2;

    // ---- stage Q,K,V via global_load_lds; source chunk index pre-permuted --
    #pragma unroll
    for (int t = 0; t < 3; ++t) {
        const unsigned short* src =
            ((t == 0) ? Q : (t == 1) ? K : V) + (size_t)b * TT * DD;
        #pragma unroll
        for (int it = 0; it < 5; ++it) {
            int flat = it * 256 + tid;              // 0..1279, need 0..1087
            if (flat < NROW * 32) {
                int row = flat >> 5, dc = flat & 31;
                int g = rbase + row;
                g = (g < 0) ? 0 : g;                 // only span 0 clamps (unused rows)
                int c = (((dc >> 2) & 3) << 3) | ((dc & 3) << 1) | ((dc >> 4) & 1);
                GLDS16(src + (size_t)g * DD + c * 8,
                       qkvs + t * (NROW * 256) + flat * 8);
            }
        }
    }
    __syncthreads();

    // ---- unit decode (waves are scale-uniform except wave 3 edge units) ----
    const int slot = tid >> 2, lq = tid & 3;
    const int head = slot & 3, u = slot >> 2;     // u = 0..15
    int ksize, LEN, w; bool active = true;
    if (u < 8)       { ksize = 1; LEN = 4096; w = s * 8 + u; }
    else if (u < 12) { ksize = 2; LEN = 2049; w = s * 4 + (u - 8); }
    else if (u < 14) { ksize = 4; LEN = 1025; w = s * 2 + (u - 12); }
    else if (u == 14){ ksize = 2; LEN = 2049; w = 512; active = (s == 127); }
    else             { ksize = 4; LEN = 1025; w = 256; active = (s == 127); }

    const int f0 = head * 64 + lq * 16;           // global feat offset
    const int fperm = head * 32 + lq * 8;         // permuted LDS in-row offset

    float accL[16];
    #pragma unroll
    for (int e = 0; e < 16; ++e) accL[e] = 0.f;

    const bool generic = (s == 0) || (s == 127);

    if (!generic) {
        // -------- fast path: rows affine in u, all positions interior -------
        if (active) {                     // u14/u15 inactive here
            float cwh[4];
            if (ksize == 1) {
                #pragma unroll
                for (int i = 0; i < 4; ++i) cwh[i] = 0.5f;
                fast_unit<1>(qkvs, u * 4 + 2, cwh, 0.125f, 1.0f, fperm, accL);
            } else if (ksize == 2) {
                #pragma unroll
                for (int i = 0; i < 4; ++i) {
                    int p = 16 * s + 4 * (u - 8) + i;
                    cwh[i] = 0.5f * (float)(((p + 1) * TT + 2048) / 2049
                                          - (p * TT + 2048) / 2049);
                }
                fast_unit<2>(qkvs, 8 * (u - 8) + 1, cwh, 0.03125f, 0.5f, fperm, accL);
            } else {
                #pragma unroll
                for (int i = 0; i < 4; ++i) {
                    int p = 8 * s + 4 * (u - 12) + i;
                    cwh[i] = 0.5f * (float)(((p + 1) * TT + 1024) / 1025
                                          - (p * TT + 1024) / 1025);
                }
                fast_unit<4>(qkvs, 16 * (u - 12), cwh, 0.0078125f, 0.25f, fperm, accL);
            }
        }
    } else if (active) {
        // -------- generic path: boundary reflect + edge windows -------------
        int rp[4]; float cwh[4]; int vmask = 0;
        for (int i = 0; i < 4; ++i) {
            int p = w * 4 + i;
            bool vv = (p < LEN);
            if (vv) vmask |= (1 << i);
            int pc = vv ? p : 0;
            int r[4] = {0, 0, 0, 0};
            if (ksize == 1) { r[0] = pc; }
            else if (ksize == 2) {
                if (pc == 0)            { r[0] = 0;      r[1] = 1;      }
                else if (pc == LEN - 1) { r[0] = TT - 2; r[1] = TT - 1; }
                else                    { r[0] = 2 * pc - 1; r[1] = 2 * pc; }
            } else {
                if (pc == 0)            { r[0] = 2; r[1] = 1; r[2] = 0; r[3] = 1; }
                else if (pc == LEN - 1) { r[0] = TT - 3; r[1] = TT - 2; r[2] = TT - 2; r[3] = TT - 1; }
                else                    { r[0] = 4*pc - 2; r[1] = 4*pc - 1; r[2] = 4*pc; r[3] = 4*pc + 1; }
            }
            int rr = 0;
            #pragma unroll
            for (int j = 0; j < 4; ++j) rr |= ((r[j] - rbase) & 0xFF) << (8 * j);
            rp[i] = rr;
            float c = 0.5f;
            if (ksize == 2)
                c = 0.5f * (float)(((p + 1) * TT + 2048) / 2049 - (p * TT + 2048) / 2049);
            else if (ksize == 4)
                c = 0.5f * (float)(((p + 1) * TT + 1024) / 1025 - (p * TT + 1024) / 1025);
            cwh[i] = vv ? c : 0.f;
        }
        const float inv_k = 1.0f / (float)ksize;
        const float sscale = 0.125f * inv_k * inv_k;

        float S[4][4];
        #pragma unroll
        for (int i = 0; i < 4; ++i)
            #pragma unroll
            for (int j = 0; j < 4; ++j) S[i][j] = 0.f;

        for (int half = 0; half < 2; ++half) {
            float qf[4][8], kf[4][8];
            const unsigned short* qb = qkvs + half * 128 + fperm;
            const unsigned short* kb = qb + NROW * 256;
            #pragma unroll
            for (int i = 0; i < 4; ++i) {
                #pragma unroll
                for (int e = 0; e < 8; ++e) { qf[i][e] = 0.f; kf[i][e] = 0.f; }
                if (vmask & (1 << i)) {
                    if (ksize == 1)      pool_qk<1>(qb, kb, rp[i], qf[i], kf[i]);
                    else if (ksize == 2) pool_qk<2>(qb, kb, rp[i], qf[i], kf[i]);
                    else                 pool_qk<4>(qb, kb, rp[i], qf[i], kf[i]);
                }
            }
            #pragma unroll
            for (int i = 0; i < 4; ++i)
                #pragma unroll
                for (int j = 0; j < 4; ++j) {
                    float d = 0.f;
                    #pragma unroll
                    for (int e = 0; e < 8; ++e) d = fmaf(qf[i][e], kf[j][e], d);
                    S[i][j] += d;
                }
        }
        #pragma unroll
        for (int i = 0; i < 4; ++i)
            #pragma unroll
            for (int j = 0; j < 4; ++j) {
                float t = S[i][j];
                t += __shfl_xor(t, 1, 64);
                t += __shfl_xor(t, 2, 64);
                S[i][j] = t * sscale;
            }
        float P[4][4];
        #pragma unroll
        for (int i = 0; i < 4; ++i) {
            float m = fmaxf(fmaxf(S[i][0], S[i][1]), fmaxf(S[i][2], S[i][3]));
            float e0 = __expf(S[i][0] - m), e1 = __expf(S[i][1] - m);
            float e2 = __expf(S[i][2] - m), e3 = __expf(S[i][3] - m);
            float inv = inv_k * __builtin_amdgcn_rcpf(e0 + e1 + e2 + e3);
            P[i][0] = e0 * inv; P[i][1] = e1 * inv; P[i][2] = e2 * inv; P[i][3] = e3 * inv;
        }
        for (int half = 0; half < 2; ++half) {
            float vf[4][8];
            const unsigned short* vb = qkvs + 2 * NROW * 256 + half * 128 + fperm;
            #pragma unroll
            for (int i = 0; i < 4; ++i) {
                #pragma unroll
                for (int e = 0; e < 8; ++e) vf[i][e] = 0.f;
                if (vmask & (1 << i)) {
                    if (ksize == 1)      pool_v<1>(vb, rp[i], vf[i]);
                    else if (ksize == 2) pool_v<2>(vb, rp[i], vf[i]);
                    else                 pool_v<4>(vb, rp[i], vf[i]);
                }
            }
            #pragma unroll
            for (int i = 0; i < 4; ++i) {
                if (!(vmask & (1 << i))) continue;
                #pragma unroll
                for (int e = 0; e < 8; ++e) {
                    float o = P[i][0]*vf[0][e] + P[i][1]*vf[1][e]
                            + P[i][2]*vf[2][e] + P[i][3]*vf[3][e];
                    accL[half * 8 + e] += cwh[i] * gelu2(o);
                }
            }
        }
    }

    // ---- block reduction over the 16 window-units, one atomic per feat ----
    __syncthreads();   // all qkvs reads done; reuse LDS as scratch
    #pragma unroll
    for (int e = 0; e < 16; e += 4) {
        float4 d = {accL[e], accL[e+1], accL[e+2], accL[e+3]};
        *(float4*)(scratch + u * 256 + f0 + e) = d;
    }
    __syncthreads();
    float sum = 0.f;
    #pragma unroll
    for (int uu = 0; uu < 16; ++uu) sum += scratch[uu * 256 + tid];
    atomicAdd(&acc[b * DD + tid], sum);
}

// ======================= classifier head ===================================
__global__ __launch_bounds__(256)
void classifier_kernel(const float* __restrict__ acc,
                       const float* __restrict__ Wp,  const float* __restrict__ bp,
                       const float* __restrict__ Wc1, const float* __restrict__ bc1,
                       const float* __restrict__ Wc2, const float* __restrict__ bc2,
                       float* __restrict__ out)
{
    const int b = blockIdx.x;
    const int d = threadIdx.x;
    __shared__ float sm[256], sf[256], sh[256];

    sm[d] = acc[b * 256 + d] * (1.0f / 4096.0f);
    __syncthreads();

    float s = bp[d];
    for (int kk = 0; kk < 256; ++kk) s = fmaf(sm[kk], Wp[kk * 256 + d], s);
    sf[d] = s;
    __syncthreads();

    s = bc1[d];
    for (int kk = 0; kk < 256; ++kk) s = fmaf(sf[kk], Wc1[kk * 256 + d], s);
    sh[d] = fmaxf(s, 0.0f);
    __syncthreads();

    if (d < 7) {
        s = bc2[d];
        for (int kk = 0; kk < 256; ++kk) s = fmaf(sh[kk], Wc2[kk * 7 + d], s);
        out[b * 7 + d] = s;
    }
}

// ======================= launch ============================================
extern "C" void kernel_launch(void* const* d_in, const int* in_sizes, int n_in,
                              void* d_out, int out_size, void* d_ws, size_t ws_size,
                              hipStream_t stream)
{
    const float* x   = (const float*)d_in[0];
    const float* Wq  = (const float*)d_in[1];
    const float* bq  = (const float*)d_in[2];
    const float* Wk  = (const float*)d_in[3];
    const float* bk  = (const float*)d_in[4];
    const float* Wv  = (const float*)d_in[5];
    const float* bv  = (const float*)d_in[6];
    const float* Wp  = (const float*)d_in[7];
    const float* bp  = (const float*)d_in[8];
    const float* Wc1 = (const float*)d_in[9];
    const float* bc1 = (const float*)d_in[10];
    const float* Wc2 = (const float*)d_in[11];
    const float* bc2 = (const float*)d_in[12];
    float* out = (float*)d_out;

    const size_t plane = (size_t)BB * TT * DD;
    unsigned short* Q  = (unsigned short*)d_ws;
    unsigned short* K  = Q + plane;
    unsigned short* V  = K + plane;
    unsigned short* Xh = V + plane;
    unsigned short* Wt = Xh + plane;
    float* acc = (float*)(Wt + 3 * 131072);

    prep_kernel<<<dim3(16384 + 768 + 1), 256, 0, stream>>>(
        x, Wq, Wk, Wv, Xh, Wt, acc);

    qkv_mfma_kernel<<<dim3(6144), 256, 0, stream>>>(
        Xh, Wt, bq, bk, bv, Q, K, V);

    attn_fused_kernel<<<dim3(128, BB), 256, 0, stream>>>(Q, K, V, acc);

    classifier_kernel<<<dim3(BB), 256, 0, stream>>>(acc, Wp, bp, Wc1, bc1, Wc2, bc2, out);
}

// Round 10
// 426.424 us; speedup vs baseline: 1.0286x; 1.0239x over previous
//
#include <hip/hip_runtime.h>

#define DD 256
#define TT 4096
#define BB 32

typedef __attribute__((ext_vector_type(8))) short short8;   // 8 bf16 (4 VGPR)
typedef __attribute__((ext_vector_type(4))) float floatx4;  // MFMA acc

// ---------- bf16 helpers (RNE via bit twiddle) ----------
__device__ __forceinline__ unsigned short f2bf(float f) {
    unsigned u = __builtin_bit_cast(unsigned, f);
    unsigned r = u + 0x7FFFu + ((u >> 16) & 1u);
    return (unsigned short)(r >> 16);
}
__device__ __forceinline__ float bf2f(unsigned short h) {
    return __builtin_bit_cast(float, (unsigned)h << 16);
}
__device__ __forceinline__ float2 unpk(unsigned u) {
    float2 r;
    r.x = __builtin_bit_cast(float, u << 16);
    r.y = __builtin_bit_cast(float, u & 0xFFFF0000u);
    return r;
}

#define GLDS16(g, l)                                                        \
    __builtin_amdgcn_global_load_lds(                                       \
        (const __attribute__((address_space(1))) void*)(g),                 \
        (__attribute__((address_space(3))) void*)(l), 16, 0, 0)

// ======================= merged prep: X->bf16 panels, W split+T, acc=0 =====
// Xp layout: [k/32][row][k%32]  (panel stride 131072*32 elements)
// Wt layout per plane: [half][k/32][n][k%32]  (half stride 65536)
__global__ __launch_bounds__(256)
void prep_kernel(const float* __restrict__ X,
                 const float* __restrict__ Wq, const float* __restrict__ Wk,
                 const float* __restrict__ Wv,
                 unsigned short* __restrict__ Xp, unsigned short* __restrict__ Wt,
                 float* __restrict__ acc)
{
    const int bid = blockIdx.x;
    const int tid = threadIdx.x;
    if (bid < 16384) {
        size_t i = ((size_t)bid * 256 + tid) * 8;
        float4 a = *(const float4*)(X + i);
        float4 b = *(const float4*)(X + i + 4);
        short8 o;
        o[0] = (short)f2bf(a.x); o[1] = (short)f2bf(a.y);
        o[2] = (short)f2bf(a.z); o[3] = (short)f2bf(a.w);
        o[4] = (short)f2bf(b.x); o[5] = (short)f2bf(b.y);
        o[6] = (short)f2bf(b.z); o[7] = (short)f2bf(b.w);
        size_t row = i >> 8;
        int k = (int)(i & 255);
        size_t off = (size_t)(k >> 5) * (131072u * 32u) + row * 32 + (k & 31);
        *(short8*)(Xp + off) = o;
    } else if (bid < 16384 + 768) {
        const int wb = bid - 16384;
        const int z = wb >> 8;
        const int k = wb & 255;
        const int n = tid;
        const float* W = (z == 0) ? Wq : (z == 1) ? Wk : Wv;
        float w = W[k * 256 + n];
        unsigned short hi = f2bf(w);
        unsigned short lo = f2bf(w - bf2f(hi));
        size_t base = (size_t)z * 131072;
        size_t off = (size_t)(k >> 5) * 8192 + (size_t)n * 32 + (k & 31);
        Wt[base +         off] = hi;
        Wt[base + 65536 + off] = lo;
    } else {
        for (int i = tid; i < BB * DD; i += 256) acc[i] = 0.f;
    }
}

// ======================= QKV GEMM: C = xh@Wh + xh@Wl (bf16 MFMA) ===========
// 16 half-steps: hi/lo weight panels alternate as K-steps, A double-buffered.
// LDS 32 KB. Chunk-XOR swizzle on BOTH sides. XCD-aware bijective remap.
__global__ __launch_bounds__(256, 4)
void qkv_mfma_kernel(const unsigned short* __restrict__ Xp,
                     const unsigned short* __restrict__ Wt,
                     const float* __restrict__ bq, const float* __restrict__ bk,
                     const float* __restrict__ bv,
                     unsigned short* __restrict__ Q, unsigned short* __restrict__ Kp,
                     unsigned short* __restrict__ V)
{
    const int d = blockIdx.x;
    const int x = d & 7, t = d >> 3;
    const int m = t / 6, zc = t - 6 * m;
    const int z = zc >> 1;
    const int col0 = (zc & 1) * 128;
    const size_t row0 = (size_t)(x + 8 * m) * 128;

    const unsigned short* Wz = Wt + (size_t)z * 131072;
    const float* bias = (z == 0) ? bq : (z == 1) ? bk : bv;
    unsigned short* Y = (z == 0) ? Q : (z == 1) ? Kp : V;

    __shared__ __align__(16) unsigned char smem[32768];

    const int tid = threadIdx.x;
    const int lane = tid & 63, wave = tid >> 6;
    const int wm = wave & 1, wn = wave >> 1;
    const int l15 = lane & 15, lq = lane >> 4;

    floatx4 acc[4][4];
    #pragma unroll
    for (int i = 0; i < 4; ++i)
        #pragma unroll
        for (int j = 0; j < 4; ++j)
            acc[i][j] = (floatx4){0.f, 0.f, 0.f, 0.f};

    auto stageA = [&](int p, int ap) {
        unsigned short* As = (unsigned short*)(smem + ap * 8192);
        const unsigned short* Apt = Xp + (size_t)p * (131072u * 32u);
        #pragma unroll
        for (int it = 0; it < 2; ++it) {
            int flat = it * 256 + tid;
            int mm = flat >> 2, c = flat & 3;
            int sc = c ^ ((mm >> 1) & 3);
            GLDS16(Apt + (row0 + mm) * 32 + sc * 8, As + flat * 8);
        }
    };
    auto stageB = [&](int p, int half, int bp) {
        unsigned short* Bs = (unsigned short*)(smem + 16384 + bp * 8192);
        const unsigned short* Bp = Wz + (size_t)half * 65536 + (size_t)p * 8192;
        #pragma unroll
        for (int it = 0; it < 2; ++it) {
            int flat = it * 256 + tid;
            int n = flat >> 2, c = flat & 3;
            int sc = c ^ ((n >> 1) & 3);
            GLDS16(Bp + (size_t)(col0 + n) * 32 + sc * 8, Bs + flat * 8);
        }
    };

    auto compute = [&](int ap, int bp) {
        const unsigned short* As = (const unsigned short*)(smem + ap * 8192);
        const unsigned short* Bs = (const unsigned short*)(smem + 16384 + bp * 8192);
        short8 a[4];
        #pragma unroll
        for (int mt = 0; mt < 4; ++mt) {
            int row = wm * 64 + mt * 16 + l15;
            a[mt] = *(const short8*)(As + row * 32 + (lq ^ ((row >> 1) & 3)) * 8);
        }
        #pragma unroll
        for (int nt = 0; nt < 4; ++nt) {
            int nr = wn * 64 + nt * 16 + l15;
            short8 bfrag = *(const short8*)(Bs + nr * 32 + (lq ^ ((nr >> 1) & 3)) * 8);
            #pragma unroll
            for (int mt = 0; mt < 4; ++mt)
                acc[mt][nt] = __builtin_amdgcn_mfma_f32_16x16x32_bf16(
                    a[mt], bfrag, acc[mt][nt], 0, 0, 0);
        }
    };

    stageA(0, 0);
    stageB(0, 0, 0);
    __syncthreads();

    for (int p = 0; p < 8; ++p) {
        const int ap = p & 1;
        stageB(p, 1, 1);
        compute(ap, 0);
        __syncthreads();
        if (p < 7) {
            stageA(p + 1, ap ^ 1);
            stageB(p + 1, 0, 0);
        }
        compute(ap, 1);
        __syncthreads();
    }

    unsigned short* Cs = (unsigned short*)(smem + wave * 8192); // [64][64] bf16
    #pragma unroll
    for (int nt = 0; nt < 4; ++nt) {
        float bv_ = bias[col0 + wn * 64 + nt * 16 + l15];
        #pragma unroll
        for (int mt = 0; mt < 4; ++mt)
            #pragma unroll
            for (int r = 0; r < 4; ++r) {
                int row = mt * 16 + lq * 4 + r;
                Cs[row * 64 + nt * 16 + l15] = f2bf(acc[mt][nt][r] + bv_);
            }
    }
    #pragma unroll
    for (int p = 0; p < 8; ++p) {
        int row = p * 8 + (lane >> 3);
        float4 dd = *(const float4*)(Cs + row * 64 + (lane & 7) * 8);
        *(float4*)(Y + (row0 + wm * 64 + row) * 256 + col0 + wn * 64 + (lane & 7) * 8) = dd;
    }
}

// ======================= fused 3-scale attention ===========================
// gelu2(x) = 2*gelu(x); 0.5 folded into cwh. A-S 7.1.26 erf (|err|<=1.5e-7).
__device__ __forceinline__ float gelu2(float x) {
    float z = fabsf(x) * 0.70710678118654752f;
    float t = __builtin_amdgcn_rcpf(fmaf(z, 0.3275911f, 1.0f));
    float p = fmaf(t, 1.061405429f, -1.453152027f);
    p = fmaf(p, t, 1.421413741f);
    p = fmaf(p, t, -0.284496736f);
    p = fmaf(p, t, 0.254829592f);
    p = p * t;
    float e = __expf(-z * z);
    float erf_abs = fmaf(-p, e, 1.0f);
    float erfv = copysignf(erf_abs, x);
    return x * (1.0f + erfv);
}
__device__ __forceinline__ void addu4(uint4 d, float* f) {
    float2 t;
    t = unpk(d.x); f[0] += t.x; f[1] += t.y;
    t = unpk(d.y); f[2] += t.x; f[3] += t.y;
    t = unpk(d.z); f[4] += t.x; f[5] += t.y;
    t = unpk(d.w); f[6] += t.x; f[7] += t.y;
}

#define SPAN 32
#define NROW 34            // span + 2 leading ghost rows

// ---- generic-path pooled gathers (rows packed as bytes in rp) ----
template<int KS>
__device__ __forceinline__ void pool_qk(const unsigned short* __restrict__ qb,
                                        const unsigned short* __restrict__ kb,
                                        int rp,
                                        float* __restrict__ qf,
                                        float* __restrict__ kf)
{
    #pragma unroll
    for (int j = 0; j < KS; ++j) {
        int ra = (rp >> (8 * j)) & 0xFF;
        uint4 qd = *(const uint4*)(qb + ra * 256);
        uint4 kd = *(const uint4*)(kb + ra * 256);
        addu4(qd, qf);
        addu4(kd, kf);
    }
}

template<int KS>
__device__ __forceinline__ void pool_v(const unsigned short* __restrict__ vb,
                                       int rp, float* __restrict__ vf)
{
    #pragma unroll
    for (int j = 0; j < KS; ++j) {
        int ra = (rp >> (8 * j)) & 0xFF;
        uint4 vd = *(const uint4*)(vb + ra * 256);
        addu4(vd, vf);
    }
}

// ---- fast-path 4-lane unit (scale 1 and 2): rows affine, interior only ----
template<int KS>
__device__ __forceinline__ void fast_unit(const unsigned short* __restrict__ qkvs,
                                          int rowbase,
                                          const float* __restrict__ cwh,
                                          float sscale, float inv_k, int fperm,
                                          float* __restrict__ accL)
{
    float S[4][4];
    #pragma unroll
    for (int i = 0; i < 4; ++i)
        #pragma unroll
        for (int j = 0; j < 4; ++j) S[i][j] = 0.f;

    #pragma unroll
    for (int half = 0; half < 2; ++half) {
        const unsigned short* qb = qkvs + half * 128 + fperm + rowbase * 256;
        const unsigned short* kb = qb + NROW * 256;
        float qf[4][8], kf[4][8];
        #pragma unroll
        for (int i = 0; i < 4; ++i) {
            #pragma unroll
            for (int e = 0; e < 8; ++e) { qf[i][e] = 0.f; kf[i][e] = 0.f; }
            #pragma unroll
            for (int j = 0; j < KS; ++j) {
                addu4(*(const uint4*)(qb + (i * KS + j) * 256), qf[i]);
                addu4(*(const uint4*)(kb + (i * KS + j) * 256), kf[i]);
            }
        }
        #pragma unroll
        for (int i = 0; i < 4; ++i)
            #pragma unroll
            for (int j = 0; j < 4; ++j) {
                float d = 0.f;
                #pragma unroll
                for (int e = 0; e < 8; ++e) d = fmaf(qf[i][e], kf[j][e], d);
                S[i][j] += d;
            }
    }
    #pragma unroll
    for (int i = 0; i < 4; ++i)
        #pragma unroll
        for (int j = 0; j < 4; ++j) {
            float t = S[i][j];
            t += __shfl_xor(t, 1, 64);
            t += __shfl_xor(t, 2, 64);
            S[i][j] = t * sscale;
        }
    float P[4][4];
    #pragma unroll
    for (int i = 0; i < 4; ++i) {
        float m = fmaxf(fmaxf(S[i][0], S[i][1]), fmaxf(S[i][2], S[i][3]));
        float e0 = __expf(S[i][0] - m), e1 = __expf(S[i][1] - m);
        float e2 = __expf(S[i][2] - m), e3 = __expf(S[i][3] - m);
        float inv = inv_k * __builtin_amdgcn_rcpf(e0 + e1 + e2 + e3);
        P[i][0] = e0 * inv; P[i][1] = e1 * inv; P[i][2] = e2 * inv; P[i][3] = e3 * inv;
    }
    #pragma unroll
    for (int half = 0; half < 2; ++half) {
        const unsigned short* vb =
            qkvs + 2 * NROW * 256 + half * 128 + fperm + rowbase * 256;
        float vf[4][8];
        #pragma unroll
        for (int i = 0; i < 4; ++i) {
            #pragma unroll
            for (int e = 0; e < 8; ++e) vf[i][e] = 0.f;
            #pragma unroll
            for (int j = 0; j < KS; ++j)
                addu4(*(const uint4*)(vb + (i * KS + j) * 256), vf[i]);
        }
        #pragma unroll
        for (int i = 0; i < 4; ++i) {
            #pragma unroll
            for (int e = 0; e < 8; ++e) {
                float o = P[i][0]*vf[0][e] + P[i][1]*vf[1][e]
                        + P[i][2]*vf[2][e] + P[i][3]*vf[3][e];
                accL[half * 8 + e] += cwh[i] * gelu2(o);
            }
        }
    }
}

// ---- fast-path 8-lane scale-4 unit: 8 lanes x 8 feats, 48 loads/lane ----
// foff = (ll&1)*128 + head*32 + (ll>>1)*8 (global feats head*64 + ll*8).
// Reduce over 8 lanes: shfl_xor 1,2,4. Fills accL[0..7] only.
__device__ __forceinline__ void fast_unit4_w8(const unsigned short* __restrict__ qkvs,
                                              int rowbase,
                                              const float* __restrict__ cwh,
                                              int foff,
                                              float* __restrict__ accL)
{
    const unsigned short* qb = qkvs + foff + rowbase * 256;
    const unsigned short* kb = qb + NROW * 256;
    float qf[4][8], kf[4][8];
    #pragma unroll
    for (int i = 0; i < 4; ++i) {
        #pragma unroll
        for (int e = 0; e < 8; ++e) { qf[i][e] = 0.f; kf[i][e] = 0.f; }
        #pragma unroll
        for (int j = 0; j < 4; ++j) {
            addu4(*(const uint4*)(qb + (i * 4 + j) * 256), qf[i]);
            addu4(*(const uint4*)(kb + (i * 4 + j) * 256), kf[i]);
        }
    }
    float S[4][4];
    #pragma unroll
    for (int i = 0; i < 4; ++i)
        #pragma unroll
        for (int j = 0; j < 4; ++j) {
            float t = 0.f;
            #pragma unroll
            for (int e = 0; e < 8; ++e) t = fmaf(qf[i][e], kf[j][e], t);
            t += __shfl_xor(t, 1, 64);
            t += __shfl_xor(t, 2, 64);
            t += __shfl_xor(t, 4, 64);
            S[i][j] = t * 0.0078125f;     // 1/8 * (1/4)^2
        }
    float P[4][4];
    #pragma unroll
    for (int i = 0; i < 4; ++i) {
        float m = fmaxf(fmaxf(S[i][0], S[i][1]), fmaxf(S[i][2], S[i][3]));
        float e0 = __expf(S[i][0] - m), e1 = __expf(S[i][1] - m);
        float e2 = __expf(S[i][2] - m), e3 = __expf(S[i][3] - m);
        float inv = 0.25f * __builtin_amdgcn_rcpf(e0 + e1 + e2 + e3);
        P[i][0] = e0 * inv; P[i][1] = e1 * inv; P[i][2] = e2 * inv; P[i][3] = e3 * inv;
    }
    const unsigned short* vb = qkvs + 2 * NROW * 256 + foff + rowbase * 256;
    float vf[4][8];
    #pragma unroll
    for (int i = 0; i < 4; ++i) {
        #pragma unroll
        for (int e = 0; e < 8; ++e) vf[i][e] = 0.f;
        #pragma unroll
        for (int j = 0; j < 4; ++j)
            addu4(*(const uint4*)(vb + (i * 4 + j) * 256), vf[i]);
    }
    #pragma unroll
    for (int i = 0; i < 4; ++i)
        #pragma unroll
        for (int e = 0; e < 8; ++e) {
            float o = P[i][0]*vf[0][e] + P[i][1]*vf[1][e]
                    + P[i][2]*vf[2][e] + P[i][3]*vf[3][e];
            accL[e] += cwh[i] * gelu2(o);
        }
}

// Block = (span s, batch b). 256 threads.
// Fast path (s in [1,126]): waves 0-1 = scale-1 (4-lane units), wave 2 =
// scale-2 (4-lane), wave 3 = scale-4 rebalanced to 8-lane units (all 64
// lanes active, 48 loads/lane vs 96 before). No edge windows interior.
// Generic path (s==0/127): original 4-lane mapping with reflect/edge code.
// End: LDS-scratch block reduction (2 barriers), ONE atomic per thread.
__global__ __launch_bounds__(256, 3)
void attn_fused_kernel(const unsigned short* __restrict__ Q,
                       const unsigned short* __restrict__ K,
                       const unsigned short* __restrict__ V,
                       float* __restrict__ acc)
{
    __shared__ __align__(16) unsigned char smem[3 * NROW * 256 * 2];  // 52224 B
    unsigned short* qkvs = (unsigned short*)smem;       // [3][NROW][256] permuted
    float* scratch = (float*)smem;                      // [16][256] overlay

    const int tid = threadIdx.x;
    const int s = blockIdx.x;          // span within batch (0..127)
    const int b = blockIdx.y;
    const int r0 = s * SPAN;
    const int rbase = r0 - 2;

    // ---- stage Q,K,V via global_load_lds; source chunk index pre-permuted --
    #pragma unroll
    for (int t = 0; t < 3; ++t) {
        const unsigned short* src =
            ((t == 0) ? Q : (t == 1) ? K : V) + (size_t)b * TT * DD;
        #pragma unroll
        for (int it = 0; it < 5; ++it) {
            int flat = it * 256 + tid;              // 0..1279, need 0..1087
            if (flat < NROW * 32) {
                int row = flat >> 5, dc = flat & 31;
                int g = rbase + row;
                g = (g < 0) ? 0 : g;                 // only span 0 clamps (unused rows)
                int c = (((dc >> 2) & 3) << 3) | ((dc & 3) << 1) | ((dc >> 4) & 1);
                GLDS16(src + (size_t)g * DD + c * 8,
                       qkvs + t * (NROW * 256) + flat * 8);
            }
        }
    }
    __syncthreads();

    float accL[16];
    #pragma unroll
    for (int e = 0; e < 16; ++e) accL[e] = 0.f;
    int rowA, colA, rowB, colB;

    const bool generic = (s == 0) || (s == 127);

    if (!generic) {
        if (tid < 192) {
            // -------- scale 1 (waves 0-1) and scale 2 (wave 2), 4-lane ------
            const int slot = tid >> 2, lq = tid & 3;
            const int head = slot & 3, u = slot >> 2;     // u in 0..11
            const int f0 = head * 64 + lq * 16;
            const int fperm = head * 32 + lq * 8;
            rowA = u; colA = f0; rowB = u; colB = f0 + 8;
            float cwh[4];
            if (u < 8) {
                #pragma unroll
                for (int i = 0; i < 4; ++i) cwh[i] = 0.5f;
                fast_unit<1>(qkvs, u * 4 + 2, cwh, 0.125f, 1.0f, fperm, accL);
            } else {
                #pragma unroll
                for (int i = 0; i < 4; ++i) {
                    int p = 16 * s + 4 * (u - 8) + i;
                    cwh[i] = 0.5f * (float)(((p + 1) * TT + 2048) / 2049
                                          - (p * TT + 2048) / 2049);
                }
                fast_unit<2>(qkvs, 8 * (u - 8) + 1, cwh, 0.03125f, 0.5f, fperm, accL);
            }
        } else {
            // -------- scale 4 (wave 3), 8-lane units --------
            const int ll = tid & 7, uid = (tid >> 3) & 7;
            const int g4 = uid >> 2, head = uid & 3;
            const int f0_4 = head * 64 + ll * 8;
            const int foff = (ll & 1) * 128 + head * 32 + (ll >> 1) * 8;
            rowA = 12 + g4; colA = f0_4;
            rowB = 14 + g4; colB = f0_4;     // accL[8..15] stay 0 -> zero rows 14/15
            float cwh[4];
            #pragma unroll
            for (int i = 0; i < 4; ++i) {
                int p = 8 * s + 4 * g4 + i;
                cwh[i] = 0.5f * (float)(((p + 1) * TT + 1024) / 1025
                                      - (p * TT + 1024) / 1025);
            }
            fast_unit4_w8(qkvs, 16 * g4, cwh, foff, accL);
        }
    } else {
        // -------- generic path: original mapping, reflect + edge windows ----
        const int slot = tid >> 2, lq = tid & 3;
        const int head = slot & 3, u = slot >> 2;     // u = 0..15
        int ksize, LEN, w; bool active = true;
        if (u < 8)       { ksize = 1; LEN = 4096; w = s * 8 + u; }
        else if (u < 12) { ksize = 2; LEN = 2049; w = s * 4 + (u - 8); }
        else if (u < 14) { ksize = 4; LEN = 1025; w = s * 2 + (u - 12); }
        else if (u == 14){ ksize = 2; LEN = 2049; w = 512; active = (s == 127); }
        else             { ksize = 4; LEN = 1025; w = 256; active = (s == 127); }

        const int f0 = head * 64 + lq * 16;
        const int fperm = head * 32 + lq * 8;
        rowA = u; colA = f0; rowB = u; colB = f0 + 8;

        if (active) {
            int rp[4]; float cwh[4]; int vmask = 0;
            for (int i = 0; i < 4; ++i) {
                int p = w * 4 + i;
                bool vv = (p < LEN);
                if (vv) vmask |= (1 << i);
                int pc = vv ? p : 0;
                int r[4] = {0, 0, 0, 0};
                if (ksize == 1) { r[0] = pc; }
                else if (ksize == 2) {
                    if (pc == 0)            { r[0] = 0;      r[1] = 1;      }
                    else if (pc == LEN - 1) { r[0] = TT - 2; r[1] = TT - 1; }
                    else                    { r[0] = 2 * pc - 1; r[1] = 2 * pc; }
                } else {
                    if (pc == 0)            { r[0] = 2; r[1] = 1; r[2] = 0; r[3] = 1; }
                    else if (pc == LEN - 1) { r[0] = TT - 3; r[1] = TT - 2; r[2] = TT - 2; r[3] = TT - 1; }
                    else                    { r[0] = 4*pc - 2; r[1] = 4*pc - 1; r[2] = 4*pc; r[3] = 4*pc + 1; }
                }
                int rr = 0;
                #pragma unroll
                for (int j = 0; j < 4; ++j) rr |= ((r[j] - rbase) & 0xFF) << (8 * j);
                rp[i] = rr;
                float c = 0.5f;
                if (ksize == 2)
                    c = 0.5f * (float)(((p + 1) * TT + 2048) / 2049 - (p * TT + 2048) / 2049);
                else if (ksize == 4)
                    c = 0.5f * (float)(((p + 1) * TT + 1024) / 1025 - (p * TT + 1024) / 1025);
                cwh[i] = vv ? c : 0.f;
            }
            const float inv_k = 1.0f / (float)ksize;
            const float sscale = 0.125f * inv_k * inv_k;

            float S[4][4];
            #pragma unroll
            for (int i = 0; i < 4; ++i)
                #pragma unroll
                for (int j = 0; j < 4; ++j) S[i][j] = 0.f;

            for (int half = 0; half < 2; ++half) {
                float qf[4][8], kf[4][8];
                const unsigned short* qb = qkvs + half * 128 + fperm;
                const unsigned short* kb = qb + NROW * 256;
                #pragma unroll
                for (int i = 0; i < 4; ++i) {
                    #pragma unroll
                    for (int e = 0; e < 8; ++e) { qf[i][e] = 0.f; kf[i][e] = 0.f; }
                    if (vmask & (1 << i)) {
                        if (ksize == 1)      pool_qk<1>(qb, kb, rp[i], qf[i], kf[i]);
                        else if (ksize == 2) pool_qk<2>(qb, kb, rp[i], qf[i], kf[i]);
                        else                 pool_qk<4>(qb, kb, rp[i], qf[i], kf[i]);
                    }
                }
                #pragma unroll
                for (int i = 0; i < 4; ++i)
                    #pragma unroll
                    for (int j = 0; j < 4; ++j) {
                        float dd = 0.f;
                        #pragma unroll
                        for (int e = 0; e < 8; ++e) dd = fmaf(qf[i][e], kf[j][e], dd);
                        S[i][j] += dd;
                    }
            }
            #pragma unroll
            for (int i = 0; i < 4; ++i)
                #pragma unroll
                for (int j = 0; j < 4; ++j) {
                    float t = S[i][j];
                    t += __shfl_xor(t, 1, 64);
                    t += __shfl_xor(t, 2, 64);
                    S[i][j] = t * sscale;
                }
            float P[4][4];
            #pragma unroll
            for (int i = 0; i < 4; ++i) {
                float m = fmaxf(fmaxf(S[i][0], S[i][1]), fmaxf(S[i][2], S[i][3]));
                float e0 = __expf(S[i][0] - m), e1 = __expf(S[i][1] - m);
                float e2 = __expf(S[i][2] - m), e3 = __expf(S[i][3] - m);
                float inv = inv_k * __builtin_amdgcn_rcpf(e0 + e1 + e2 + e3);
                P[i][0] = e0 * inv; P[i][1] = e1 * inv; P[i][2] = e2 * inv; P[i][3] = e3 * inv;
            }
            for (int half = 0; half < 2; ++half) {
                float vf[4][8];
                const unsigned short* vb = qkvs + 2 * NROW * 256 + half * 128 + fperm;
                #pragma unroll
                for (int i = 0; i < 4; ++i) {
                    #pragma unroll
                    for (int e = 0; e < 8; ++e) vf[i][e] = 0.f;
                    if (vmask & (1 << i)) {
                        if (ksize == 1)      pool_v<1>(vb, rp[i], vf[i]);
                        else if (ksize == 2) pool_v<2>(vb, rp[i], vf[i]);
                        else                 pool_v<4>(vb, rp[i], vf[i]);
                    }
                }
                #pragma unroll
                for (int i = 0; i < 4; ++i) {
                    if (!(vmask & (1 << i))) continue;
                    #pragma unroll
                    for (int e = 0; e < 8; ++e) {
                        float o = P[i][0]*vf[0][e] + P[i][1]*vf[1][e]
                                + P[i][2]*vf[2][e] + P[i][3]*vf[3][e];
                        accL[half * 8 + e] += cwh[i] * gelu2(o);
                    }
                }
            }
        }
    }

    // ---- block reduction over the 16 scratch rows, one atomic per feat ----
    __syncthreads();   // all qkvs reads done; reuse LDS as scratch
    {
        float4 dA0 = {accL[0], accL[1], accL[2], accL[3]};
        float4 dA1 = {accL[4], accL[5], accL[6], accL[7]};
        float4 dB0 = {accL[8], accL[9], accL[10], accL[11]};
        float4 dB1 = {accL[12], accL[13], accL[14], accL[15]};
        *(float4*)(scratch + rowA * 256 + colA)     = dA0;
        *(float4*)(scratch + rowA * 256 + colA + 4) = dA1;
        *(float4*)(scratch + rowB * 256 + colB)     = dB0;
        *(float4*)(scratch + rowB * 256 + colB + 4) = dB1;
    }
    __syncthreads();
    float sum = 0.f;
    #pragma unroll
    for (int uu = 0; uu < 16; ++uu) sum += scratch[uu * 256 + tid];
    atomicAdd(&acc[b * DD + tid], sum);
}

// ======================= classifier head ===================================
__global__ __launch_bounds__(256)
void classifier_kernel(const float* __restrict__ acc,
                       const float* __restrict__ Wp,  const float* __restrict__ bp,
                       const float* __restrict__ Wc1, const float* __restrict__ bc1,
                       const float* __restrict__ Wc2, const float* __restrict__ bc2,
                       float* __restrict__ out)
{
    const int b = blockIdx.x;
    const int d = threadIdx.x;
    __shared__ float sm[256], sf[256], sh[256];

    sm[d] = acc[b * 256 + d] * (1.0f / 4096.0f);
    __syncthreads();

    float s = bp[d];
    for (int kk = 0; kk < 256; ++kk) s = fmaf(sm[kk], Wp[kk * 256 + d], s);
    sf[d] = s;
    __syncthreads();

    s = bc1[d];
    for (int kk = 0; kk < 256; ++kk) s = fmaf(sf[kk], Wc1[kk * 256 + d], s);
    sh[d] = fmaxf(s, 0.0f);
    __syncthreads();

    if (d < 7) {
        s = bc2[d];
        for (int kk = 0; kk < 256; ++kk) s = fmaf(sh[kk], Wc2[kk * 7 + d], s);
        out[b * 7 + d] = s;
    }
}

// ======================= launch ============================================
extern "C" void kernel_launch(void* const* d_in, const int* in_sizes, int n_in,
                              void* d_out, int out_size, void* d_ws, size_t ws_size,
                              hipStream_t stream)
{
    const float* x   = (const float*)d_in[0];
    const float* Wq  = (const float*)d_in[1];
    const float* bq  = (const float*)d_in[2];
    const float* Wk  = (const float*)d_in[3];
    const float* bk  = (const float*)d_in[4];
    const float* Wv  = (const float*)d_in[5];
    const float* bv  = (const float*)d_in[6];
    const float* Wp  = (const float*)d_in[7];
    const float* bp  = (const float*)d_in[8];
    const float* Wc1 = (const float*)d_in[9];
    const float* bc1 = (const float*)d_in[10];
    const float* Wc2 = (const float*)d_in[11];
    const float* bc2 = (const float*)d_in[12];
    float* out = (float*)d_out;

    const size_t plane = (size_t)BB * TT * DD;
    unsigned short* Q  = (unsigned short*)d_ws;
    unsigned short* K  = Q + plane;
    unsigned short* V  = K + plane;
    unsigned short* Xh = V + plane;
    unsigned short* Wt = Xh + plane;
    float* acc = (float*)(Wt + 3 * 131072);

    prep_kernel<<<dim3(16384 + 768 + 1), 256, 0, stream>>>(
        x, Wq, Wk, Wv, Xh, Wt, acc);

    qkv_mfma_kernel<<<dim3(6144), 256, 0, stream>>>(
        Xh, Wt, bq, bk, bv, Q, K, V);

    attn_fused_kernel<<<dim3(128, BB), 256, 0, stream>>>(Q, K, V, acc);

    classifier_kernel<<<dim3(BB), 256, 0, stream>>>(acc, Wp, bp, Wc1, bc1, Wc2, bc2, out);
}